// Round 2
// baseline (235.586 us; speedup 1.0000x reference)
//
#include <hip/hip_runtime.h>

// out[16384,64] = f32(multi_hot[16384,10000]) @ embed[10000,64]
// Memory-bound on the 655 MB multi_hot stream (ideal ~100us @ 6.6 TB/s).
//
// v2.1: barrier-free redesign (v2 had a grid-size bug: 128 blocks -> only
// seg 0 computed; need 512 blocks for 512 rowblks x 4 K-segments).
//   prep kernel: embed f32 [10000][64] -> Bt bf16 [64][10240] in d_ws
//                (fragment-ready [n][k] layout, k zero-padded), + zero out[].
//   main kernel: no LDS, no barriers. Each wave owns 32 rows x 64 cols x a
//                K-segment (split-K x4 -> 2048 waves = 8/CU), register
//                double-buffered A (nontemporal global) + B (L2-hit) loads,
//                counted-vmcnt pipelining by the compiler, f32 atomicAdd out.

typedef int    int4v   __attribute__((ext_vector_type(4)));
typedef float  float4v __attribute__((ext_vector_type(4)));
typedef float  f32x4   __attribute__((ext_vector_type(4)));
typedef short  bf16x8  __attribute__((ext_vector_type(8)));
typedef unsigned int uint4v __attribute__((ext_vector_type(4)));

constexpr int M_DIM   = 16384;
constexpr int K_DIM   = 10000;
constexpr int N_DIM   = 64;
constexpr int BK      = 64;
constexpr int NCH_PAD = 160;           // ceil(10000/64)=157, pad to 160 (4x40)
constexpr int KPAD    = NCH_PAD * BK;  // 10240 bf16 per Bt row
constexpr int SPLIT   = 4;
constexpr int NCH_SEG = NCH_PAD / SPLIT;  // 40 chunks per K-segment
constexpr int WM      = 32;            // rows per wave (2 m-tiles of 16)

__device__ __forceinline__ unsigned f2bf(float x) {   // f32 -> bf16 bits, RNE
    unsigned u = __builtin_bit_cast(unsigned, x);
    u += 0x7FFFu + ((u >> 16) & 1u);
    return u >> 16;
}

// ---------------------------------------------------------------------------
// prep: blocks [0,160): transpose+convert embed -> Bt[n][k] bf16 (k>=10000 -> 0)
//       blocks [160,416): zero out[] (must precede main kernel's atomics)
// ---------------------------------------------------------------------------
__global__ __launch_bounds__(256) void prep(const float* __restrict__ em,
                                            unsigned short* __restrict__ bt,
                                            float* __restrict__ out) {
    const int tid = threadIdx.x;
    const int b   = blockIdx.x;
    if (b < NCH_PAD) {
        __shared__ float t[64][65];            // [n][k], +1 pad
        const int k0 = b * 64;
        #pragma unroll
        for (int rep = 0; rep < 16; ++rep) {   // coalesced 64x64 f32 read
            const int idx = rep * 256 + tid;
            const int k = idx >> 6, n = idx & 63;
            float v = 0.f;
            if (k0 + k < K_DIM) v = em[(k0 + k) * N_DIM + n];
            t[n][k] = v;
        }
        __syncthreads();
        const int n  = tid >> 2;               // 0..63
        const int kk = (tid & 3) * 16;         // 0..48
        unsigned w[8];
        #pragma unroll
        for (int j = 0; j < 8; ++j)
            w[j] = f2bf(t[n][kk + 2 * j]) | (f2bf(t[n][kk + 2 * j + 1]) << 16);
        uint4v lo = {w[0], w[1], w[2], w[3]};
        uint4v hi = {w[4], w[5], w[6], w[7]};
        uint4v* dst = (uint4v*)(bt + (long long)n * KPAD + k0 + kk);
        dst[0] = lo; dst[1] = hi;              // 32B contiguous per thread
    } else {
        const int b2 = b - NCH_PAD;            // 0..255
        float4v z = {0.f, 0.f, 0.f, 0.f};
        float4v* p = (float4v*)out;
        const int base = b2 * 256 + tid;
        #pragma unroll
        for (int i = 0; i < 4; ++i) p[base + i * 65536] = z;  // 4.19 MB total
    }
}

// ---------------------------------------------------------------------------
// main GEMM: 512 blocks x 256 thr (2048 waves). wave w = bid*4+wv; seg = w>>9
// (4 waves of a block share a segment -> L1 reuse of the B chunk stream),
// rowblk = w&511.
// ---------------------------------------------------------------------------
struct ARegs { int4v q0, q1, q2, q3; };        // one 16-row m-tile, 64 k ints
struct BF    { bf16x8 f[4][2]; };              // [n-tile][k-step] fragments

__global__ __launch_bounds__(256, 2) void mhe_gemm(
        const int* __restrict__ mh, const unsigned short* __restrict__ bt,
        float* __restrict__ out) {
    const int tid  = threadIdx.x;
    const int lane = tid & 63;
    const int wv   = tid >> 6;
    const int w    = (int)blockIdx.x * 4 + wv;     // 0..2047
    const int seg  = w >> 9;                       // 0..3
    const int rowblk = w & 511;
    const int row0 = rowblk * WM;
    const int c0   = seg * NCH_SEG;

    const int g8 = (lane >> 4) << 3;               // k sub-offset within k-step
    const int* __restrict__ ap0 = mh + (long long)(row0 + (lane & 15)) * K_DIM;
    const int* __restrict__ ap1 = ap0 + (long long)16 * K_DIM;

    // B fragment row base: lane reads Bt[nt*16 + (lane&15)][c*64 + ks*32 + g8 ..+7]
    const unsigned short* __restrict__ bpn[4];
    #pragma unroll
    for (int nt = 0; nt < 4; ++nt)
        bpn[nt] = bt + (long long)(nt * 16 + (lane & 15)) * KPAD + g8;

    f32x4 acc[2][4] = {};

    // ints 0/1 -> packed bf16 pairs: (a | b<<16) * 0x3F80 == bf16(a) | bf16(b)<<16
    auto packA = [&](int4v qa, int4v qb) -> bf16x8 {
        uint4v x;
        x[0] = (unsigned)(qa[0] | (qa[1] << 16)) * 0x3F80u;
        x[1] = (unsigned)(qa[2] | (qa[3] << 16)) * 0x3F80u;
        x[2] = (unsigned)(qb[0] | (qb[1] << 16)) * 0x3F80u;
        x[3] = (unsigned)(qb[2] | (qb[3] << 16)) * 0x3F80u;
        return __builtin_bit_cast(bf16x8, x);
    };

    auto loadAB = [&](ARegs& x0, ARegs& x1, BF& bb, int c) {
        const int f0 = c * BK;
        if (f0 + BK <= K_DIM) {                    // fast path: chunks 0..155
            const int4v* p0 = (const int4v*)(ap0 + f0 + g8);
            const int4v* p1 = (const int4v*)(ap0 + f0 + 32 + g8);
            const int4v* p2 = (const int4v*)(ap1 + f0 + g8);
            const int4v* p3 = (const int4v*)(ap1 + f0 + 32 + g8);
            x0.q0 = __builtin_nontemporal_load(p0);      // A streams once:
            x0.q1 = __builtin_nontemporal_load(p0 + 1);  // keep Bt in L2
            x0.q2 = __builtin_nontemporal_load(p1);
            x0.q3 = __builtin_nontemporal_load(p1 + 1);
            x1.q0 = __builtin_nontemporal_load(p2);
            x1.q1 = __builtin_nontemporal_load(p2 + 1);
            x1.q2 = __builtin_nontemporal_load(p3);
            x1.q3 = __builtin_nontemporal_load(p3 + 1);
        } else {                                   // chunks 156..159 (K tail)
            x0.q0 = {}; x0.q1 = {}; x0.q2 = {}; x0.q3 = {};
            x1.q0 = {}; x1.q1 = {}; x1.q2 = {}; x1.q3 = {};
            const int b0 = f0 + g8;
            if (b0      < K_DIM) { x0.q0 = *(const int4v*)(ap0 + b0);
                                   x1.q0 = *(const int4v*)(ap1 + b0); }
            if (b0 + 4  < K_DIM) { x0.q1 = *(const int4v*)(ap0 + b0 + 4);
                                   x1.q1 = *(const int4v*)(ap1 + b0 + 4); }
            if (b0 + 32 < K_DIM) { x0.q2 = *(const int4v*)(ap0 + b0 + 32);
                                   x1.q2 = *(const int4v*)(ap1 + b0 + 32); }
            if (b0 + 36 < K_DIM) { x0.q3 = *(const int4v*)(ap0 + b0 + 36);
                                   x1.q3 = *(const int4v*)(ap1 + b0 + 36); }
        }
        #pragma unroll
        for (int nt = 0; nt < 4; ++nt) {           // B: L2-resident bf16, padded
            bb.f[nt][0] = *(const bf16x8*)(bpn[nt] + f0);
            bb.f[nt][1] = *(const bf16x8*)(bpn[nt] + f0 + 32);
        }
    };

    auto compute = [&](const ARegs& x0, const ARegs& x1, const BF& bb) {
        bf16x8 a00 = packA(x0.q0, x0.q1);          // m-tile 0, k 0..31
        bf16x8 a01 = packA(x0.q2, x0.q3);          // m-tile 0, k 32..63
        bf16x8 a10 = packA(x1.q0, x1.q1);
        bf16x8 a11 = packA(x1.q2, x1.q3);
        #pragma unroll
        for (int nt = 0; nt < 4; ++nt) {
            acc[0][nt] = __builtin_amdgcn_mfma_f32_16x16x32_bf16(a00, bb.f[nt][0], acc[0][nt], 0, 0, 0);
            acc[0][nt] = __builtin_amdgcn_mfma_f32_16x16x32_bf16(a01, bb.f[nt][1], acc[0][nt], 0, 0, 0);
            acc[1][nt] = __builtin_amdgcn_mfma_f32_16x16x32_bf16(a10, bb.f[nt][0], acc[1][nt], 0, 0, 0);
            acc[1][nt] = __builtin_amdgcn_mfma_f32_16x16x32_bf16(a11, bb.f[nt][1], acc[1][nt], 0, 0, 0);
        }
    };

    // register-double-buffered K loop, NO barriers: compiler keeps the next
    // chunk's 16 loads in flight via counted vmcnt across iterations.
    ARegs a0A, a1A, a0B, a1B;
    BF bA, bB;
    loadAB(a0A, a1A, bA, c0);
    int c = c0;
    for (; c + 2 < c0 + NCH_SEG; c += 2) {
        loadAB(a0B, a1B, bB, c + 1);
        compute(a0A, a1A, bA);
        loadAB(a0A, a1A, bA, c + 2);
        compute(a0B, a1B, bB);
    }
    loadAB(a0B, a1B, bB, c + 1);
    compute(a0A, a1A, bA);
    compute(a0B, a1B, bB);

    // C/D layout: col = lane&15, row = (lane>>4)*4 + i   [m89-verified]
    const int crow = row0 + ((lane >> 4) << 2);
    const int ccol = lane & 15;
    #pragma unroll
    for (int mt = 0; mt < 2; ++mt)
        #pragma unroll
        for (int nt = 0; nt < 4; ++nt)
            #pragma unroll
            for (int i = 0; i < 4; ++i)
                unsafeAtomicAdd(&out[(long long)(crow + mt * 16 + i) * N_DIM + nt * 16 + ccol],
                                acc[mt][nt][i]);
}

extern "C" void kernel_launch(void* const* d_in, const int* in_sizes, int n_in,
                              void* d_out, int out_size, void* d_ws, size_t ws_size,
                              hipStream_t stream) {
    const int*   mh  = (const int*)d_in[0];
    const float* em  = (const float*)d_in[1];
    float*       out = (float*)d_out;
    unsigned short* bt = (unsigned short*)d_ws;    // needs 64*10240*2 = 1.31 MB
    (void)in_sizes; (void)n_in; (void)out_size; (void)ws_size;

    prep<<<dim3(NCH_PAD + 256), dim3(256), 0, stream>>>(em, bt, out);
    mhe_gemm<<<dim3((M_DIM / WM) * SPLIT / 4), dim3(256), 0, stream>>>(mh, bt, out);
}